// Round 1
// baseline (2972.948 us; speedup 1.0000x reference)
//
#include <hip/hip_runtime.h>

// ---------------------------------------------------------------------------
// Net_19378892440061: Open3D-style ContinuousConv fluid network.
//   wall_1  = relu(cconv(wall_normal, wall->fluid, W_wall1))      [16000,32]
//   fluid_1 = relu(cconv(fluid_vel, fluid->fluid, W_fluid1))      [16000,32]
//   dense_1 = fluid_vel @ W_d1 + b_d1                             [16000,32]
//   out_1 = concat -> [16000,96]
//   out_2 = relu(cconv(out_1) + out_1@W_d2 + b_c2 + b_d2)         [16000,64]
//   out_3 = relu(out_2 + cconv(out_2) + out_2@W_d3 + b_c3+b_d3)   [16000,64]
//   out   = cconv(out_3) + out_3@W_d4 + b_c4 + b_d4               [16000,3]
//
// Strategy: per cconv, build im2col-style A[n, 64*cin (+cin dense tail)] via
// LDS scatter (each thread owns one channel column -> no atomics), then a
// tiled fp32 GEMM with fused bias/residual/relu epilogue. Geometry (window,
// trilinear coords) precomputed once per neighbor-pair and reused by all
// layers sharing that neighbor list.
//
// Neighbor masks are NOT read from the bool inputs (byte layout unknown);
// they are reconstructed: flatnonzero gives strictly ascending indices, so
// nbr[k]==0 at k>0 is padding; k==0 validity is recomputed with bit-exact
// fp32 distance (contract off) + fp64 compare, matching numpy.
// ---------------------------------------------------------------------------

#define M_FLUID 16000
#define KNBR 64

__device__ __forceinline__ float sgnf(float v) {
    return (v > 0.f) ? 1.f : ((v < 0.f) ? -1.f : 0.f);
}

// Volume-preserving ball->cube map (matches reference _ball_to_cube, fp32).
__device__ __forceinline__ void ball_to_cube(float x, float y, float z,
                                             float& xc, float& yc, float& zc) {
    const float eps = 1e-12f;
    float sq  = x*x + y*y + z*z;
    float nrm = sqrtf(fmaxf(sq, eps));
    float rho = sqrtf(fmaxf(x*x + y*y, eps));
    bool  top = (1.25f*z*z > x*x + y*y);
    float s_top = sqrtf(3.0f*nrm/(nrm + fabsf(z)));
    float xs = top ? x*s_top : x*nrm/rho;
    float ys = top ? y*s_top : y*nrm/rho;
    float zs = top ? sgnf(z)*nrm : 1.5f*z;
    if (sq < eps) { xs = 0.f; ys = 0.f; zs = 0.f; }
    float rxy = sqrtf(fmaxf(xs*xs + ys*ys, eps));
    bool use_x = fabsf(ys) <= fabsf(xs);
    float dx = (use_x && fabsf(xs) > eps) ? xs : 1.0f;
    float dy = (!use_x && fabsf(ys) > eps) ? ys : 1.0f;
    const float c4pi = 1.2732395447351628f;  // 4/pi
    float xc_, yc_;
    if (use_x) {
        xc_ = sgnf(xs)*rxy;
        yc_ = sgnf(xs)*rxy*c4pi*atanf(ys/dx);
    } else {
        xc_ = sgnf(ys)*rxy*c4pi*atanf(xs/dy);
        yc_ = sgnf(ys)*rxy;
    }
    if (xs*xs + ys*ys < eps) { xc_ = 0.f; yc_ = 0.f; }
    xc = xc_; yc = yc_; zc = zs;
}

// Per-pair geometry: win (0 if invalid), trilinear fractions f, packed cell.
__global__ void geom_kernel(const float* __restrict__ pos_in,
                            const float* __restrict__ pos_out,
                            const int*  __restrict__ nbr,
                            float4* __restrict__ geomF,
                            int*    __restrict__ geomI,
                            int M, int excl_self) {
    int t = blockIdx.x * blockDim.x + threadIdx.x;
    if (t >= M * KNBR) return;
    int n = t >> 6;
    int k = t & 63;
    int j = nbr[t];
    float px = pos_out[n*3+0], py = pos_out[n*3+1], pz = pos_out[n*3+2];
    float qx = pos_in[(size_t)j*3+0], qy = pos_in[(size_t)j*3+1], qz = pos_in[(size_t)j*3+2];
    float dx = qx - px, dy = qy - py, dz = qz - pz;

    bool valid;
    if (k == 0) {
        // reproduce numpy fp32 distance exactly (no FMA contraction)
#pragma clang fp contract(off)
        float d2f = dx*dx + dy*dy;
        d2f = d2f + dz*dz;
        double d2 = (double)d2f;
        const double RADIUS_D = 0.5*(6.0*1.5*0.025);  // 0.1125
        valid = d2 < RADIUS_D*RADIUS_D;
        if (excl_self) valid = valid && (d2 > 1e-18);
    } else {
        valid = (j != 0);  // ascending neighbor ids: 0 past slot 0 == padding
    }

    const float Rf = (float)(0.5*(6.0*1.5*0.025));
    float ux = dx / Rf, uy = dy / Rf, uz = dz / Rf;
    float r2 = ux*ux + uy*uy; r2 += uz*uz;
    float w1 = 1.f - r2;
    float win = fminf(fmaxf(w1*w1*w1, 0.f), 1.f);

    float bx, by, bz;
    ball_to_cube(ux, uy, uz, bx, by, bz);
    float cx = fminf(fmaxf((bx*0.5f + 0.5f)*3.f, 0.f), 3.f);
    float cy = fminf(fmaxf((by*0.5f + 0.5f)*3.f, 0.f), 3.f);
    float cz = fminf(fmaxf((bz*0.5f + 0.5f)*3.f, 0.f), 3.f);
    float ix = fminf(fmaxf(floorf(cx), 0.f), 2.f);
    float iy = fminf(fmaxf(floorf(cy), 0.f), 2.f);
    float iz = fminf(fmaxf(floorf(cz), 0.f), 2.f);
    float fx = cx - ix, fy = cy - iy, fz = cz - iz;
    int cell = ((int)ix*4 + (int)iy)*4 + (int)iz;

    geomF[t] = make_float4(valid ? win : 0.f, fx, fy, fz);
    geomI[t] = cell;
}

// Build A rows [m0..m1): scatter part (64 cells * CIN) + optional dense tail.
// Thread (c,p) owns channel column c of particle p -> no atomics, no barriers.
template<int CIN, int P>
__global__ void abuild_kernel(const float* __restrict__ feat,
                              const int*   __restrict__ nbr,
                              const float4* __restrict__ geomF,
                              const int*   __restrict__ geomI,
                              const float* __restrict__ dense,
                              float* __restrict__ A,
                              int m0, int m1, int Ktot) {
    __shared__ float Ash[P][64*CIN];
    int c = threadIdx.x;
    int p = threadIdx.y;
    int n = m0 + blockIdx.x * P + p;
    float* col = Ash[p];
#pragma unroll
    for (int cell = 0; cell < 64; ++cell) col[cell*CIN + c] = 0.f;
    if (n >= m1) return;

    const int*    nrow = nbr   + (size_t)n * KNBR;
    const float4* grow = geomF + (size_t)n * KNBR;
    const int*    irow = geomI + (size_t)n * KNBR;
    for (int k = 0; k < KNBR; ++k) {
        float4 g = grow[k];
        float win = g.x;
        if (win <= 0.f) continue;
        int j = nrow[k];
        int base = irow[k];
        float v = feat[(size_t)j*CIN + c] * win;
        float wx1 = g.y, wy1 = g.z, wz1 = g.w;
        float wx0 = 1.f - wx1, wy0 = 1.f - wy1, wz0 = 1.f - wz1;
        float w00 = wy0*wz0, w01 = wy0*wz1, w10 = wy1*wz0, w11 = wy1*wz1;
        float* cb = col + base*CIN + c;
        cb[0*CIN]  += wx0*w00*v;
        cb[1*CIN]  += wx0*w01*v;
        cb[4*CIN]  += wx0*w10*v;
        cb[5*CIN]  += wx0*w11*v;
        cb[16*CIN] += wx1*w00*v;
        cb[17*CIN] += wx1*w01*v;
        cb[20*CIN] += wx1*w10*v;
        cb[21*CIN] += wx1*w11*v;
    }
    float* Arow = A + (size_t)(n - m0) * Ktot;
#pragma unroll
    for (int cell = 0; cell < 64; ++cell) Arow[cell*CIN + c] = col[cell*CIN + c];
    if (dense) Arow[64*CIN + c] = dense[(size_t)n*CIN + c];
}

// dense_1 = fluid_vel @ W_d1 + b_d1 -> out1 columns [64..96)
__global__ void dense1_kernel(const float* __restrict__ vel,
                              const float* __restrict__ Wd,
                              const float* __restrict__ bd,
                              float* __restrict__ out1, int M) {
    int t = blockIdx.x * blockDim.x + threadIdx.x;
    if (t >= M*32) return;
    int n = t >> 5, c = t & 31;
    float v = bd[c] + vel[n*3+0]*Wd[c] + vel[n*3+1]*Wd[32+c] + vel[n*3+2]*Wd[64+c];
    out1[(size_t)n*96 + 64 + c] = v;
}

// Tiled fp32 GEMM: out[m, ocol+c] = f(A[m,:] @ [Wa;Wb] + b1 (+b2) (+res)).
// TM=64, TN=64, KC=32; 256 threads; 4x4 micro-tile; N<=64, Ktot % 32 == 0.
#define GTM 64
#define GKC 32
__global__ __launch_bounds__(256) void gemm_kernel(
        const float* __restrict__ A, int Ktot,
        const float* __restrict__ Wa, int K1,
        const float* __restrict__ Wb,
        const float* __restrict__ b1, const float* __restrict__ b2,
        const float* __restrict__ res,
        float* __restrict__ out, int ostride, int ocol,
        int m_base, int rows, int N, int relu) {
    __shared__ float Ash[GKC][GTM+4];
    __shared__ float Wsh[GKC][64+4];
    int tid = threadIdx.x;
    int mblk = blockIdx.x * GTM;
    if (mblk >= rows) return;
    int tr = tid >> 4, tc = tid & 15;
    int r0 = tr*4, c0 = tc*4;
    float acc[4][4] = {};

    for (int k0 = 0; k0 < Ktot; k0 += GKC) {
#pragma unroll
        for (int i = 0; i < 2; ++i) {       // A tile: 64 rows x 32 k
            int g = tid + 256*i;
            int row = g >> 3, kk = (g & 7)*4;
            float4 a = make_float4(0.f,0.f,0.f,0.f);
            int arow = mblk + row;
            if (arow < rows) a = *(const float4*)&A[(size_t)arow*Ktot + k0 + kk];
            Ash[kk+0][row] = a.x; Ash[kk+1][row] = a.y;
            Ash[kk+2][row] = a.z; Ash[kk+3][row] = a.w;
        }
#pragma unroll
        for (int i = 0; i < 2; ++i) {       // W tile: 32 k x 64 n (zero pad n>=N)
            int g = tid + 256*i;
            int kk = g >> 4, c4 = (g & 15)*4;
            float4 w = make_float4(0.f,0.f,0.f,0.f);
            if (c4 < N) {
                int k = k0 + kk;
                const float* src = (k < K1) ? &Wa[(size_t)k*N + c4]
                                            : &Wb[(size_t)(k-K1)*N + c4];
                w = *(const float4*)src;
            }
            *(float4*)&Wsh[kk][c4] = w;
        }
        __syncthreads();
#pragma unroll
        for (int kk = 0; kk < GKC; ++kk) {
            float4 a = *(const float4*)&Ash[kk][r0];
            float4 b = *(const float4*)&Wsh[kk][c0];
            float av[4] = {a.x, a.y, a.z, a.w};
            float bv[4] = {b.x, b.y, b.z, b.w};
#pragma unroll
            for (int i = 0; i < 4; ++i)
#pragma unroll
                for (int jj = 0; jj < 4; ++jj)
                    acc[i][jj] += av[i]*bv[jj];
        }
        __syncthreads();
    }

#pragma unroll
    for (int i = 0; i < 4; ++i) {
        int m = mblk + r0 + i;
        if (m >= rows) continue;
        int n_abs = m_base + m;
#pragma unroll
        for (int jj = 0; jj < 4; ++jj) {
            int c = c0 + jj;
            if (c >= N) continue;
            float v = acc[i][jj] + b1[c];
            if (b2) v += b2[c];
            if (res) v += res[(size_t)n_abs*64 + c];
            if (relu) v = fmaxf(v, 0.f);
            out[(size_t)n_abs*ostride + ocol + c] = v;
        }
    }
}

// Final layer (N=3): per-wave GEMV, W (4160x3 = 49.9KB) staged in LDS.
#define K4TOT 4160
__global__ __launch_bounds__(256) void gemv3_kernel(
        const float* __restrict__ A,
        const float* __restrict__ Wa, int K1elems,
        const float* __restrict__ Wb,
        const float* __restrict__ b1, const float* __restrict__ b2,
        float* __restrict__ out, int m_base, int rows) {
    __shared__ float Wsh[K4TOT*3];
    int tid = threadIdx.x;
    for (int i = tid; i < K4TOT*3; i += 256)
        Wsh[i] = (i < K1elems) ? Wa[i] : Wb[i - K1elems];
    __syncthreads();
    int wv = tid >> 6, l = tid & 63;
    int m = blockIdx.x*4 + wv;
    if (m >= rows) return;
    const float* Arow = A + (size_t)m * K4TOT;
    float a0 = 0.f, a1 = 0.f, a2 = 0.f;
    for (int k = l; k < K4TOT; k += 64) {
        float a = Arow[k];
        a0 += a*Wsh[k*3+0];
        a1 += a*Wsh[k*3+1];
        a2 += a*Wsh[k*3+2];
    }
#pragma unroll
    for (int off = 32; off; off >>= 1) {
        a0 += __shfl_down(a0, off, 64);
        a1 += __shfl_down(a1, off, 64);
        a2 += __shfl_down(a2, off, 64);
    }
    if (l == 0) {
        int n = m_base + m;
        out[n*3+0] = a0 + b1[0] + b2[0];
        out[n*3+1] = a1 + b1[1] + b2[1];
        out[n*3+2] = a2 + b1[2] + b2[2];
    }
}

extern "C" void kernel_launch(void* const* d_in, const int* in_sizes, int n_in,
                              void* d_out, int out_size, void* d_ws, size_t ws_size,
                              hipStream_t stream) {
    const float* fluid_pos = (const float*)d_in[0];
    const float* wall_pos  = (const float*)d_in[1];
    const float* fluid_vel = (const float*)d_in[2];
    const float* wall_nrm  = (const float*)d_in[3];
    const int*   nbr_wf    = (const int*)d_in[4];
    const int*   nbr_ff    = (const int*)d_in[6];
    const float* W_wall1   = (const float*)d_in[8];
    const float* b_wall1   = (const float*)d_in[9];
    const float* W_fluid1  = (const float*)d_in[10];
    const float* b_fluid1  = (const float*)d_in[11];
    const float* W_d1      = (const float*)d_in[12];
    const float* b_d1      = (const float*)d_in[13];
    const float* W_c2      = (const float*)d_in[14];
    const float* b_c2      = (const float*)d_in[15];
    const float* W_d2      = (const float*)d_in[16];
    const float* b_d2      = (const float*)d_in[17];
    const float* W_c3      = (const float*)d_in[18];
    const float* b_c3      = (const float*)d_in[19];
    const float* W_d3      = (const float*)d_in[20];
    const float* b_d3      = (const float*)d_in[21];
    const float* W_c4      = (const float*)d_in[22];
    const float* b_c4      = (const float*)d_in[23];
    const float* W_d4      = (const float*)d_in[24];
    const float* b_d4      = (const float*)d_in[25];

    const int M = M_FLUID;
    char* ws = (char*)d_ws;
    size_t off = 0;
    auto carve = [&](size_t bytes) {
        char* p = ws + off;
        off = (off + bytes + 255) & ~(size_t)255;
        return p;
    };
    float4* gF_ff = (float4*)carve((size_t)M*KNBR*sizeof(float4));
    int*    gI_ff = (int*)   carve((size_t)M*KNBR*4);
    float4* gF_wf = (float4*)carve((size_t)M*KNBR*sizeof(float4));
    int*    gI_wf = (int*)   carve((size_t)M*KNBR*4);
    float*  out1  = (float*) carve((size_t)M*96*4);
    float*  out2  = (float*) carve((size_t)M*64*4);
    float*  out3  = (float*) carve((size_t)M*64*4);
    float*  Abuf  = (float*)(ws + off);
    size_t availA = (ws_size > off) ? (ws_size - off) : 0;

    auto chunkR = [&](int Ktot) -> int {
        size_t r = availA / ((size_t)Ktot * 4);
        if (r > (size_t)M) r = (size_t)M;
        r &= ~(size_t)63;
        if (r < 64) r = 64;   // assume ws large enough for at least 64 rows
        return (int)r;
    };

    {   // geometry (reused across all layers sharing the neighbor list)
        int total = M * KNBR, thr = 256, blk = (total + thr - 1) / thr;
        geom_kernel<<<blk, thr, 0, stream>>>(fluid_pos, fluid_pos, nbr_ff, gF_ff, gI_ff, M, 1);
        geom_kernel<<<blk, thr, 0, stream>>>(wall_pos,  fluid_pos, nbr_wf, gF_wf, gI_wf, M, 0);
    }
    dense1_kernel<<<(M*32 + 255)/256, 256, 0, stream>>>(fluid_vel, W_d1, b_d1, out1, M);

    // ---- layer 1a: wall cconv -> out1[:, 0:32]
    {
        int Ktot = 192, R = chunkR(Ktot);
        for (int m0 = 0; m0 < M; m0 += R) {
            int rows = (M - m0 < R) ? (M - m0) : R;
            abuild_kernel<3,64><<<(rows+63)/64, dim3(3,64), 0, stream>>>(
                wall_nrm, nbr_wf, gF_wf, gI_wf, nullptr, Abuf, m0, m0+rows, Ktot);
            gemm_kernel<<<(rows+GTM-1)/GTM, 256, 0, stream>>>(
                Abuf, Ktot, W_wall1, Ktot, nullptr, b_wall1, nullptr, nullptr,
                out1, 96, 0, m0, rows, 32, 1);
        }
    }
    // ---- layer 1b: fluid cconv -> out1[:, 32:64]
    {
        int Ktot = 192, R = chunkR(Ktot);
        for (int m0 = 0; m0 < M; m0 += R) {
            int rows = (M - m0 < R) ? (M - m0) : R;
            abuild_kernel<3,64><<<(rows+63)/64, dim3(3,64), 0, stream>>>(
                fluid_vel, nbr_ff, gF_ff, gI_ff, nullptr, Abuf, m0, m0+rows, Ktot);
            gemm_kernel<<<(rows+GTM-1)/GTM, 256, 0, stream>>>(
                Abuf, Ktot, W_fluid1, Ktot, nullptr, b_fluid1, nullptr, nullptr,
                out1, 96, 32, m0, rows, 32, 1);
        }
    }
    // ---- layer 2: cin=96 -> out2
    {
        int Ktot = 6240, K1 = 6144, R = chunkR(Ktot);
        for (int m0 = 0; m0 < M; m0 += R) {
            int rows = (M - m0 < R) ? (M - m0) : R;
            abuild_kernel<96,2><<<(rows+1)/2, dim3(96,2), 0, stream>>>(
                out1, nbr_ff, gF_ff, gI_ff, out1, Abuf, m0, m0+rows, Ktot);
            gemm_kernel<<<(rows+GTM-1)/GTM, 256, 0, stream>>>(
                Abuf, Ktot, W_c2, K1, W_d2, b_c2, b_d2, nullptr,
                out2, 64, 0, m0, rows, 64, 1);
        }
    }
    // ---- layer 3: cin=64, residual -> out3
    {
        int Ktot = 4160, K1 = 4096, R = chunkR(Ktot);
        for (int m0 = 0; m0 < M; m0 += R) {
            int rows = (M - m0 < R) ? (M - m0) : R;
            abuild_kernel<64,3><<<(rows+2)/3, dim3(64,3), 0, stream>>>(
                out2, nbr_ff, gF_ff, gI_ff, out2, Abuf, m0, m0+rows, Ktot);
            gemm_kernel<<<(rows+GTM-1)/GTM, 256, 0, stream>>>(
                Abuf, Ktot, W_c3, K1, W_d3, b_c3, b_d3, out2,
                out3, 64, 0, m0, rows, 64, 1);
        }
    }
    // ---- layer 4: cin=64, N=3 -> d_out
    {
        int Ktot = K4TOT, R = chunkR(Ktot);
        for (int m0 = 0; m0 < M; m0 += R) {
            int rows = (M - m0 < R) ? (M - m0) : R;
            abuild_kernel<64,3><<<(rows+2)/3, dim3(64,3), 0, stream>>>(
                out3, nbr_ff, gF_ff, gI_ff, out3, Abuf, m0, m0+rows, Ktot);
            gemv3_kernel<<<(rows+3)/4, 256, 0, stream>>>(
                Abuf, W_c4, 4096*3, W_d4, b_c4, b_d4, (float*)d_out, m0, rows);
        }
    }
}

// Round 2
// 1342.844 us; speedup vs baseline: 2.2139x; 2.2139x over previous
//
#include <hip/hip_runtime.h>
#include <hip/hip_bf16.h>

// ---------------------------------------------------------------------------
// Net_19378892440061: ContinuousConv fluid network, Round 2.
// Changes vs Round 1:
//  - A matrix (im2col) stored in bf16; weights pre-transposed to bf16 Wt[n][k].
//  - GEMM replaced by LDS-free bf16 MFMA kernel (16x16x32), fp32 accumulate,
//    16-row M-tile x 4-way wave K-split, small padded-LDS cross-wave reduce.
//  - gemv3 (final N=3 layer) reads bf16 A, fp32 weights in LDS.
// ---------------------------------------------------------------------------

#define M_FLUID 16000
#define KNBR 64

typedef __attribute__((ext_vector_type(8))) short bf16x8;
typedef __attribute__((ext_vector_type(4))) float f32x4;

__device__ __forceinline__ ushort f2bf(float f) {
    __hip_bfloat16 h = __float2bfloat16(f);   // RNE
    return *(ushort*)&h;
}
__device__ __forceinline__ float bfbits2f(uint hi16) {
    union { uint u; float f; } cv; cv.u = hi16; return cv.f;
}

__device__ __forceinline__ float sgnf(float v) {
    return (v > 0.f) ? 1.f : ((v < 0.f) ? -1.f : 0.f);
}

// Volume-preserving ball->cube map (matches reference _ball_to_cube, fp32).
__device__ __forceinline__ void ball_to_cube(float x, float y, float z,
                                             float& xc, float& yc, float& zc) {
    const float eps = 1e-12f;
    float sq  = x*x + y*y + z*z;
    float nrm = sqrtf(fmaxf(sq, eps));
    float rho = sqrtf(fmaxf(x*x + y*y, eps));
    bool  top = (1.25f*z*z > x*x + y*y);
    float s_top = sqrtf(3.0f*nrm/(nrm + fabsf(z)));
    float xs = top ? x*s_top : x*nrm/rho;
    float ys = top ? y*s_top : y*nrm/rho;
    float zs = top ? sgnf(z)*nrm : 1.5f*z;
    if (sq < eps) { xs = 0.f; ys = 0.f; zs = 0.f; }
    float rxy = sqrtf(fmaxf(xs*xs + ys*ys, eps));
    bool use_x = fabsf(ys) <= fabsf(xs);
    float dx = (use_x && fabsf(xs) > eps) ? xs : 1.0f;
    float dy = (!use_x && fabsf(ys) > eps) ? ys : 1.0f;
    const float c4pi = 1.2732395447351628f;  // 4/pi
    float xc_, yc_;
    if (use_x) {
        xc_ = sgnf(xs)*rxy;
        yc_ = sgnf(xs)*rxy*c4pi*atanf(ys/dx);
    } else {
        xc_ = sgnf(ys)*rxy*c4pi*atanf(xs/dy);
        yc_ = sgnf(ys)*rxy;
    }
    if (xs*xs + ys*ys < eps) { xc_ = 0.f; yc_ = 0.f; }
    xc = xc_; yc = yc_; zc = zs;
}

// Per-pair geometry: win (0 if invalid), trilinear fractions f, packed cell.
__global__ void geom_kernel(const float* __restrict__ pos_in,
                            const float* __restrict__ pos_out,
                            const int*  __restrict__ nbr,
                            float4* __restrict__ geomF,
                            int*    __restrict__ geomI,
                            int M, int excl_self) {
    int t = blockIdx.x * blockDim.x + threadIdx.x;
    if (t >= M * KNBR) return;
    int n = t >> 6;
    int k = t & 63;
    int j = nbr[t];
    float px = pos_out[n*3+0], py = pos_out[n*3+1], pz = pos_out[n*3+2];
    float qx = pos_in[(size_t)j*3+0], qy = pos_in[(size_t)j*3+1], qz = pos_in[(size_t)j*3+2];
    float dx = qx - px, dy = qy - py, dz = qz - pz;

    bool valid;
    if (k == 0) {
        // reproduce numpy fp32 distance exactly (no FMA contraction)
#pragma clang fp contract(off)
        float d2f = dx*dx + dy*dy;
        d2f = d2f + dz*dz;
        double d2 = (double)d2f;
        const double RADIUS_D = 0.5*(6.0*1.5*0.025);  // 0.1125
        valid = d2 < RADIUS_D*RADIUS_D;
        if (excl_self) valid = valid && (d2 > 1e-18);
    } else {
        valid = (j != 0);  // ascending neighbor ids: 0 past slot 0 == padding
    }

    const float Rf = (float)(0.5*(6.0*1.5*0.025));
    float ux = dx / Rf, uy = dy / Rf, uz = dz / Rf;
    float r2 = ux*ux + uy*uy; r2 += uz*uz;
    float w1 = 1.f - r2;
    float win = fminf(fmaxf(w1*w1*w1, 0.f), 1.f);

    float bx, by, bz;
    ball_to_cube(ux, uy, uz, bx, by, bz);
    float cx = fminf(fmaxf((bx*0.5f + 0.5f)*3.f, 0.f), 3.f);
    float cy = fminf(fmaxf((by*0.5f + 0.5f)*3.f, 0.f), 3.f);
    float cz = fminf(fmaxf((bz*0.5f + 0.5f)*3.f, 0.f), 3.f);
    float ix = fminf(fmaxf(floorf(cx), 0.f), 2.f);
    float iy = fminf(fmaxf(floorf(cy), 0.f), 2.f);
    float iz = fminf(fmaxf(floorf(cz), 0.f), 2.f);
    float fx = cx - ix, fy = cy - iy, fz = cz - iz;
    int cell = ((int)ix*4 + (int)iy)*4 + (int)iz;

    geomF[t] = make_float4(valid ? win : 0.f, fx, fy, fz);
    geomI[t] = cell;
}

// Build A rows [m0..m1) in bf16: scatter (64 cells * CIN) + optional dense tail.
// Thread (c,p) owns channel column c of particle p -> no atomics, no barriers.
// Accumulation stays fp32 in LDS; only the writeback is bf16.
template<int CIN, int P>
__global__ void abuild_kernel(const float* __restrict__ feat,
                              const int*   __restrict__ nbr,
                              const float4* __restrict__ geomF,
                              const int*   __restrict__ geomI,
                              const float* __restrict__ dense,
                              ushort* __restrict__ A,
                              int m0, int m1, int Ktot) {
    __shared__ float Ash[P][64*CIN];
    int c = threadIdx.x;
    int p = threadIdx.y;
    int n = m0 + blockIdx.x * P + p;
    float* col = Ash[p];
#pragma unroll
    for (int cell = 0; cell < 64; ++cell) col[cell*CIN + c] = 0.f;
    if (n >= m1) return;

    const int*    nrow = nbr   + (size_t)n * KNBR;
    const float4* grow = geomF + (size_t)n * KNBR;
    const int*    irow = geomI + (size_t)n * KNBR;
    for (int k = 0; k < KNBR; ++k) {
        float4 g = grow[k];
        float win = g.x;
        if (win <= 0.f) continue;
        int j = nrow[k];
        int base = irow[k];
        float v = feat[(size_t)j*CIN + c] * win;
        float wx1 = g.y, wy1 = g.z, wz1 = g.w;
        float wx0 = 1.f - wx1, wy0 = 1.f - wy1, wz0 = 1.f - wz1;
        float w00 = wy0*wz0, w01 = wy0*wz1, w10 = wy1*wz0, w11 = wy1*wz1;
        float* cb = col + base*CIN + c;
        cb[0*CIN]  += wx0*w00*v;
        cb[1*CIN]  += wx0*w01*v;
        cb[4*CIN]  += wx0*w10*v;
        cb[5*CIN]  += wx0*w11*v;
        cb[16*CIN] += wx1*w00*v;
        cb[17*CIN] += wx1*w01*v;
        cb[20*CIN] += wx1*w10*v;
        cb[21*CIN] += wx1*w11*v;
    }
    ushort* Arow = A + (size_t)(n - m0) * Ktot;
#pragma unroll
    for (int cell = 0; cell < 64; ++cell) Arow[cell*CIN + c] = f2bf(col[cell*CIN + c]);
    if (dense) Arow[64*CIN + c] = f2bf(dense[(size_t)n*CIN + c]);
}

// dense_1 = fluid_vel @ W_d1 + b_d1 -> out1 columns [64..96)
__global__ void dense1_kernel(const float* __restrict__ vel,
                              const float* __restrict__ Wd,
                              const float* __restrict__ bd,
                              float* __restrict__ out1, int M) {
    int t = blockIdx.x * blockDim.x + threadIdx.x;
    if (t >= M*32) return;
    int n = t >> 5, c = t & 31;
    float v = bd[c] + vel[n*3+0]*Wd[c] + vel[n*3+1]*Wd[32+c] + vel[n*3+2]*Wd[64+c];
    out1[(size_t)n*96 + 64 + c] = v;
}

// Transpose + bf16-convert weights: Wt[n][k] from Wc (Kc x N) ++ Wd ((Ktot-Kc) x N).
__global__ void wprep_kernel(const float* __restrict__ Wc, int Kc,
                             const float* __restrict__ Wd,
                             int N, ushort* __restrict__ Wt, int Ktot) {
    int t = blockIdx.x * blockDim.x + threadIdx.x;
    if (t >= N * Ktot) return;
    int n = t / Ktot, k = t - n * Ktot;
    float v = (k < Kc) ? Wc[(size_t)k*N + n] : Wd[(size_t)(k-Kc)*N + n];
    Wt[(size_t)n*Ktot + k] = f2bf(v);
}

// LDS-free bf16 MFMA GEMM: out[m, ocol+c] = f(A[m,:] @ Wt^T + b1 (+b2) (+res)).
// Block = 16-row M-tile x (NCT*16) cols; 4 waves split K (stride-4 over
// 32-wide k-steps); A/B fragments loaded straight from global (16B/lane).
// Cross-wave fp32 reduce via padded LDS (stride NCT*16+2 -> conflict-free).
template<int NCT>
__global__ __launch_bounds__(256) void mfma_gemm_kernel(
        const ushort* __restrict__ A, int Ktot,
        const ushort* __restrict__ Wt,
        const float* __restrict__ b1, const float* __restrict__ b2,
        const float* __restrict__ res,
        float* __restrict__ out, int ostride, int ocol,
        int m_base, int relu) {
    __shared__ float red[4][16][NCT*16 + 2];
    int tid = threadIdx.x;
    int wave = tid >> 6, l = tid & 63;
    int m0 = blockIdx.x * 16;
    int lm = l & 15;        // A/B row within tile
    int lk = l >> 4;        // k-octet
    f32x4 acc[NCT];
#pragma unroll
    for (int ct = 0; ct < NCT; ++ct) acc[ct] = (f32x4){0.f, 0.f, 0.f, 0.f};

    int nks = Ktot >> 5;
    const ushort* Arow = A  + (size_t)(m0 + lm) * Ktot + lk*8;
    const ushort* Wrow = Wt + (size_t)lm * Ktot + lk*8;
    for (int ks = wave; ks < nks; ks += 4) {
        int k0 = ks * 32;
        bf16x8 a = *(const bf16x8*)(Arow + k0);
#pragma unroll
        for (int ct = 0; ct < NCT; ++ct) {
            bf16x8 b = *(const bf16x8*)(Wrow + (size_t)ct*16*Ktot + k0);
            acc[ct] = __builtin_amdgcn_mfma_f32_16x16x32_bf16(a, b, acc[ct], 0, 0, 0);
        }
    }

    // C/D layout: col = lane&15, row = (lane>>4)*4 + reg  [m89/m91]
#pragma unroll
    for (int ct = 0; ct < NCT; ++ct)
#pragma unroll
        for (int r = 0; r < 4; ++r)
            red[wave][lk*4 + r][ct*16 + lm] = acc[ct][r];
    __syncthreads();

    const int NT = NCT * 16;
    for (int idx = tid; idx < 16*NT; idx += 256) {
        int row = idx / NT, col = idx - row*NT;
        float v = red[0][row][col] + red[1][row][col]
                + red[2][row][col] + red[3][row][col];
        int n_abs = m_base + m0 + row;
        v += b1[col];
        if (b2) v += b2[col];
        if (res) v += res[(size_t)n_abs*64 + col];
        if (relu) v = fmaxf(v, 0.f);
        out[(size_t)n_abs*ostride + ocol + col] = v;
    }
}

// Final layer (N=3): per-wave GEMV over bf16 A, fp32 W (49.9KB) staged in LDS.
#define K4TOT 4160
__global__ __launch_bounds__(256) void gemv3_kernel(
        const ushort* __restrict__ A,
        const float* __restrict__ Wa, int K1elems,
        const float* __restrict__ Wb,
        const float* __restrict__ b1, const float* __restrict__ b2,
        float* __restrict__ out, int m_base, int rows) {
    __shared__ float Wsh[K4TOT*3];
    int tid = threadIdx.x;
    for (int i = tid; i < K4TOT*3; i += 256)
        Wsh[i] = (i < K1elems) ? Wa[i] : Wb[i - K1elems];
    __syncthreads();
    int wv = tid >> 6, l = tid & 63;
    int m = blockIdx.x*4 + wv;
    if (m >= rows) return;
    const ushort* Arow = A + (size_t)m * K4TOT;
    float a0 = 0.f, a1 = 0.f, a2 = 0.f;
    // 4160 = 32 * 128 + 64: 32 paired iterations + 64-wide tail
#pragma unroll 4
    for (int i = 0; i < 32; ++i) {
        int k = 2*l + 128*i;
        uint pr = *(const uint*)(Arow + k);
        float x0 = bfbits2f(pr << 16);
        float x1 = bfbits2f(pr & 0xFFFF0000u);
        a0 += x0*Wsh[k*3+0] + x1*Wsh[(k+1)*3+0];
        a1 += x0*Wsh[k*3+1] + x1*Wsh[(k+1)*3+1];
        a2 += x0*Wsh[k*3+2] + x1*Wsh[(k+1)*3+2];
    }
    {
        int k = 4096 + l;
        float x = bfbits2f(((uint)Arow[k]) << 16);
        a0 += x*Wsh[k*3+0];
        a1 += x*Wsh[k*3+1];
        a2 += x*Wsh[k*3+2];
    }
#pragma unroll
    for (int off = 32; off; off >>= 1) {
        a0 += __shfl_down(a0, off, 64);
        a1 += __shfl_down(a1, off, 64);
        a2 += __shfl_down(a2, off, 64);
    }
    if (l == 0) {
        int n = m_base + m;
        out[n*3+0] = a0 + b1[0] + b2[0];
        out[n*3+1] = a1 + b1[1] + b2[1];
        out[n*3+2] = a2 + b1[2] + b2[2];
    }
}

extern "C" void kernel_launch(void* const* d_in, const int* in_sizes, int n_in,
                              void* d_out, int out_size, void* d_ws, size_t ws_size,
                              hipStream_t stream) {
    const float* fluid_pos = (const float*)d_in[0];
    const float* wall_pos  = (const float*)d_in[1];
    const float* fluid_vel = (const float*)d_in[2];
    const float* wall_nrm  = (const float*)d_in[3];
    const int*   nbr_wf    = (const int*)d_in[4];
    const int*   nbr_ff    = (const int*)d_in[6];
    const float* W_wall1   = (const float*)d_in[8];
    const float* b_wall1   = (const float*)d_in[9];
    const float* W_fluid1  = (const float*)d_in[10];
    const float* b_fluid1  = (const float*)d_in[11];
    const float* W_d1      = (const float*)d_in[12];
    const float* b_d1      = (const float*)d_in[13];
    const float* W_c2      = (const float*)d_in[14];
    const float* b_c2      = (const float*)d_in[15];
    const float* W_d2      = (const float*)d_in[16];
    const float* b_d2      = (const float*)d_in[17];
    const float* W_c3      = (const float*)d_in[18];
    const float* b_c3      = (const float*)d_in[19];
    const float* W_d3      = (const float*)d_in[20];
    const float* b_d3      = (const float*)d_in[21];
    const float* W_c4      = (const float*)d_in[22];
    const float* b_c4      = (const float*)d_in[23];
    const float* W_d4      = (const float*)d_in[24];
    const float* b_d4      = (const float*)d_in[25];

    const int M = M_FLUID;
    char* ws = (char*)d_ws;
    size_t off = 0;
    auto carve = [&](size_t bytes) {
        char* p = ws + off;
        off = (off + bytes + 255) & ~(size_t)255;
        return p;
    };
    float4* gF_ff = (float4*)carve((size_t)M*KNBR*sizeof(float4));
    int*    gI_ff = (int*)   carve((size_t)M*KNBR*4);
    float4* gF_wf = (float4*)carve((size_t)M*KNBR*sizeof(float4));
    int*    gI_wf = (int*)   carve((size_t)M*KNBR*4);
    float*  out1  = (float*) carve((size_t)M*96*4);
    float*  out2  = (float*) carve((size_t)M*64*4);
    float*  out3  = (float*) carve((size_t)M*64*4);
    ushort* Wt1a  = (ushort*)carve((size_t)32*192*2);
    ushort* Wt1b  = (ushort*)carve((size_t)32*192*2);
    ushort* Wt2   = (ushort*)carve((size_t)64*6240*2);
    ushort* Wt3   = (ushort*)carve((size_t)64*4160*2);
    ushort* Abuf  = (ushort*)(ws + off);
    size_t availA = (ws_size > off) ? (ws_size - off) : 0;

    auto chunkR = [&](int Ktot) -> int {
        size_t r = availA / ((size_t)Ktot * 2);   // bf16 A
        if (r > (size_t)M) r = (size_t)M;
        r &= ~(size_t)63;
        if (r < 64) r = 64;   // assume ws large enough for at least 64 rows
        return (int)r;
    };

    // ---- weight prep (bf16 transpose)
    {
        int t;
        t = 32*192;  wprep_kernel<<<(t+255)/256, 256, 0, stream>>>(W_wall1, 192, nullptr, 32, Wt1a, 192);
        t = 32*192;  wprep_kernel<<<(t+255)/256, 256, 0, stream>>>(W_fluid1, 192, nullptr, 32, Wt1b, 192);
        t = 64*6240; wprep_kernel<<<(t+255)/256, 256, 0, stream>>>(W_c2, 6144, W_d2, 64, Wt2, 6240);
        t = 64*4160; wprep_kernel<<<(t+255)/256, 256, 0, stream>>>(W_c3, 4096, W_d3, 64, Wt3, 4160);
    }
    {   // geometry (reused across all layers sharing the neighbor list)
        int total = M * KNBR, thr = 256, blk = (total + thr - 1) / thr;
        geom_kernel<<<blk, thr, 0, stream>>>(fluid_pos, fluid_pos, nbr_ff, gF_ff, gI_ff, M, 1);
        geom_kernel<<<blk, thr, 0, stream>>>(wall_pos,  fluid_pos, nbr_wf, gF_wf, gI_wf, M, 0);
    }
    dense1_kernel<<<(M*32 + 255)/256, 256, 0, stream>>>(fluid_vel, W_d1, b_d1, out1, M);

    // ---- layer 1a: wall cconv -> out1[:, 0:32]
    {
        int Ktot = 192, R = chunkR(Ktot);
        for (int m0 = 0; m0 < M; m0 += R) {
            int rows = (M - m0 < R) ? (M - m0) : R;
            abuild_kernel<3,64><<<(rows+63)/64, dim3(3,64), 0, stream>>>(
                wall_nrm, nbr_wf, gF_wf, gI_wf, nullptr, Abuf, m0, m0+rows, Ktot);
            mfma_gemm_kernel<2><<<rows/16, 256, 0, stream>>>(
                Abuf, Ktot, Wt1a, b_wall1, nullptr, nullptr,
                out1, 96, 0, m0, 1);
        }
    }
    // ---- layer 1b: fluid cconv -> out1[:, 32:64]
    {
        int Ktot = 192, R = chunkR(Ktot);
        for (int m0 = 0; m0 < M; m0 += R) {
            int rows = (M - m0 < R) ? (M - m0) : R;
            abuild_kernel<3,64><<<(rows+63)/64, dim3(3,64), 0, stream>>>(
                fluid_vel, nbr_ff, gF_ff, gI_ff, nullptr, Abuf, m0, m0+rows, Ktot);
            mfma_gemm_kernel<2><<<rows/16, 256, 0, stream>>>(
                Abuf, Ktot, Wt1b, b_fluid1, nullptr, nullptr,
                out1, 96, 32, m0, 1);
        }
    }
    // ---- layer 2: cin=96 -> out2
    {
        int Ktot = 6240, R = chunkR(Ktot);
        for (int m0 = 0; m0 < M; m0 += R) {
            int rows = (M - m0 < R) ? (M - m0) : R;
            abuild_kernel<96,2><<<(rows+1)/2, dim3(96,2), 0, stream>>>(
                out1, nbr_ff, gF_ff, gI_ff, out1, Abuf, m0, m0+rows, Ktot);
            mfma_gemm_kernel<4><<<rows/16, 256, 0, stream>>>(
                Abuf, Ktot, Wt2, b_c2, b_d2, nullptr,
                out2, 64, 0, m0, 1);
        }
    }
    // ---- layer 3: cin=64, residual -> out3
    {
        int Ktot = 4160, R = chunkR(Ktot);
        for (int m0 = 0; m0 < M; m0 += R) {
            int rows = (M - m0 < R) ? (M - m0) : R;
            abuild_kernel<64,3><<<(rows+2)/3, dim3(64,3), 0, stream>>>(
                out2, nbr_ff, gF_ff, gI_ff, out2, Abuf, m0, m0+rows, Ktot);
            mfma_gemm_kernel<4><<<rows/16, 256, 0, stream>>>(
                Abuf, Ktot, Wt3, b_c3, b_d3, out2,
                out3, 64, 0, m0, 1);
        }
    }
    // ---- layer 4: cin=64, N=3 -> d_out
    {
        int Ktot = K4TOT, R = chunkR(Ktot);
        for (int m0 = 0; m0 < M; m0 += R) {
            int rows = (M - m0 < R) ? (M - m0) : R;
            abuild_kernel<64,3><<<(rows+2)/3, dim3(64,3), 0, stream>>>(
                out3, nbr_ff, gF_ff, gI_ff, out3, Abuf, m0, m0+rows, Ktot);
            gemv3_kernel<<<(rows+3)/4, 256, 0, stream>>>(
                Abuf, W_c4, 4096*3, W_d4, b_c4, b_d4, (float*)d_out, m0, rows);
        }
    }
}

// Round 3
// 623.511 us; speedup vs baseline: 4.7681x; 2.1537x over previous
//
#include <hip/hip_runtime.h>
#include <hip/hip_bf16.h>

// ---------------------------------------------------------------------------
// Net_19378892440061: ContinuousConv fluid network, Round 3.
// Changes vs Round 2:
//  - abuild for cin>=64 reformulated as per-particle MFMA:
//      A[cell,ch] = sum_k S[cell,k] * fw[k,ch]
//    S[64x64] = trilinear*window scatter matrix (8 nz/col, built with 8 bf16
//    LDS writes per neighbor), fw = bf16(feat rows). One wave per particle,
//    wave-synchronous (no barriers). 48 (cin96) / 32 (cin64) MFMAs/particle.
//  - A stored in permuted K-order k' = ch*64 + cell (conv part) so the MFMA
//    C-layout writes back contiguously; wprep/gemv3 permute weights to match.
//  - Layer-1 (cin=3) keeps the round-2 scalar scatter path (k = cell*3+ch).
// ---------------------------------------------------------------------------

#define M_FLUID 16000
#define KNBR 64

typedef __attribute__((ext_vector_type(8))) short bf16x8;
typedef __attribute__((ext_vector_type(4))) float f32x4;
typedef __attribute__((ext_vector_type(4))) unsigned short u16x4;

__device__ __forceinline__ ushort f2bf(float f) {
    __hip_bfloat16 h = __float2bfloat16(f);   // RNE
    return *(ushort*)&h;
}
__device__ __forceinline__ float bfbits2f(uint hi16) {
    union { uint u; float f; } cv; cv.u = hi16; return cv.f;
}

__device__ __forceinline__ float sgnf(float v) {
    return (v > 0.f) ? 1.f : ((v < 0.f) ? -1.f : 0.f);
}

// Volume-preserving ball->cube map (matches reference _ball_to_cube, fp32).
__device__ __forceinline__ void ball_to_cube(float x, float y, float z,
                                             float& xc, float& yc, float& zc) {
    const float eps = 1e-12f;
    float sq  = x*x + y*y + z*z;
    float nrm = sqrtf(fmaxf(sq, eps));
    float rho = sqrtf(fmaxf(x*x + y*y, eps));
    bool  top = (1.25f*z*z > x*x + y*y);
    float s_top = sqrtf(3.0f*nrm/(nrm + fabsf(z)));
    float xs = top ? x*s_top : x*nrm/rho;
    float ys = top ? y*s_top : y*nrm/rho;
    float zs = top ? sgnf(z)*nrm : 1.5f*z;
    if (sq < eps) { xs = 0.f; ys = 0.f; zs = 0.f; }
    float rxy = sqrtf(fmaxf(xs*xs + ys*ys, eps));
    bool use_x = fabsf(ys) <= fabsf(xs);
    float dx = (use_x && fabsf(xs) > eps) ? xs : 1.0f;
    float dy = (!use_x && fabsf(ys) > eps) ? ys : 1.0f;
    const float c4pi = 1.2732395447351628f;  // 4/pi
    float xc_, yc_;
    if (use_x) {
        xc_ = sgnf(xs)*rxy;
        yc_ = sgnf(xs)*rxy*c4pi*atanf(ys/dx);
    } else {
        xc_ = sgnf(ys)*rxy*c4pi*atanf(xs/dy);
        yc_ = sgnf(ys)*rxy;
    }
    if (xs*xs + ys*ys < eps) { xc_ = 0.f; yc_ = 0.f; }
    xc = xc_; yc = yc_; zc = zs;
}

// Per-pair geometry: win (0 if invalid), trilinear fractions f, packed cell.
__global__ void geom_kernel(const float* __restrict__ pos_in,
                            const float* __restrict__ pos_out,
                            const int*  __restrict__ nbr,
                            float4* __restrict__ geomF,
                            int*    __restrict__ geomI,
                            int M, int excl_self) {
    int t = blockIdx.x * blockDim.x + threadIdx.x;
    if (t >= M * KNBR) return;
    int n = t >> 6;
    int k = t & 63;
    int j = nbr[t];
    float px = pos_out[n*3+0], py = pos_out[n*3+1], pz = pos_out[n*3+2];
    float qx = pos_in[(size_t)j*3+0], qy = pos_in[(size_t)j*3+1], qz = pos_in[(size_t)j*3+2];
    float dx = qx - px, dy = qy - py, dz = qz - pz;

    bool valid;
    if (k == 0) {
        // reproduce numpy fp32 distance exactly (no FMA contraction)
#pragma clang fp contract(off)
        float d2f = dx*dx + dy*dy;
        d2f = d2f + dz*dz;
        double d2 = (double)d2f;
        const double RADIUS_D = 0.5*(6.0*1.5*0.025);  // 0.1125
        valid = d2 < RADIUS_D*RADIUS_D;
        if (excl_self) valid = valid && (d2 > 1e-18);
    } else {
        valid = (j != 0);  // ascending neighbor ids: 0 past slot 0 == padding
    }

    const float Rf = (float)(0.5*(6.0*1.5*0.025));
    float ux = dx / Rf, uy = dy / Rf, uz = dz / Rf;
    float r2 = ux*ux + uy*uy; r2 += uz*uz;
    float w1 = 1.f - r2;
    float win = fminf(fmaxf(w1*w1*w1, 0.f), 1.f);

    float bx, by, bz;
    ball_to_cube(ux, uy, uz, bx, by, bz);
    float cx = fminf(fmaxf((bx*0.5f + 0.5f)*3.f, 0.f), 3.f);
    float cy = fminf(fmaxf((by*0.5f + 0.5f)*3.f, 0.f), 3.f);
    float cz = fminf(fmaxf((bz*0.5f + 0.5f)*3.f, 0.f), 3.f);
    float ix = fminf(fmaxf(floorf(cx), 0.f), 2.f);
    float iy = fminf(fmaxf(floorf(cy), 0.f), 2.f);
    float iz = fminf(fmaxf(floorf(cz), 0.f), 2.f);
    float fx = cx - ix, fy = cy - iy, fz = cz - iz;
    int cell = ((int)ix*4 + (int)iy)*4 + (int)iz;

    geomF[t] = make_float4(valid ? win : 0.f, fx, fy, fz);
    geomI[t] = cell;
}

// ---- Layer-1 path (cin=3): round-2 scalar scatter, k = cell*3+ch order.
template<int CIN, int P>
__global__ void abuild_kernel(const float* __restrict__ feat,
                              const int*   __restrict__ nbr,
                              const float4* __restrict__ geomF,
                              const int*   __restrict__ geomI,
                              ushort* __restrict__ A,
                              int m0, int m1, int Ktot) {
    __shared__ float Ash[P][64*CIN];
    int c = threadIdx.x;
    int p = threadIdx.y;
    int n = m0 + blockIdx.x * P + p;
    float* col = Ash[p];
#pragma unroll
    for (int cell = 0; cell < 64; ++cell) col[cell*CIN + c] = 0.f;
    if (n >= m1) return;

    const int*    nrow = nbr   + (size_t)n * KNBR;
    const float4* grow = geomF + (size_t)n * KNBR;
    const int*    irow = geomI + (size_t)n * KNBR;
    for (int k = 0; k < KNBR; ++k) {
        float4 g = grow[k];
        float win = g.x;
        if (win <= 0.f) continue;
        int j = nrow[k];
        int base = irow[k];
        float v = feat[(size_t)j*CIN + c] * win;
        float wx1 = g.y, wy1 = g.z, wz1 = g.w;
        float wx0 = 1.f - wx1, wy0 = 1.f - wy1, wz0 = 1.f - wz1;
        float w00 = wy0*wz0, w01 = wy0*wz1, w10 = wy1*wz0, w11 = wy1*wz1;
        float* cb = col + base*CIN + c;
        cb[0*CIN]  += wx0*w00*v;
        cb[1*CIN]  += wx0*w01*v;
        cb[4*CIN]  += wx0*w10*v;
        cb[5*CIN]  += wx0*w11*v;
        cb[16*CIN] += wx1*w00*v;
        cb[17*CIN] += wx1*w01*v;
        cb[20*CIN] += wx1*w10*v;
        cb[21*CIN] += wx1*w11*v;
    }
    ushort* Arow = A + (size_t)(n - m0) * Ktot;
#pragma unroll
    for (int cell = 0; cell < 64; ++cell) Arow[cell*CIN + c] = f2bf(col[cell*CIN + c]);
}

// ---- MFMA-scatter abuild for CIN in {64, 96}. One wave = one particle.
// S[64 cells][72] bf16 (tri*win weights, k columns), FW[CIN ch][72] bf16
// (neighbor features, transposed), A_t reuses FW. K-order out: k'=ch*64+cell,
// then dense tail bf16(dense[n]).
template<int CIN>
__global__ __launch_bounds__(64) void abuild_s_kernel(
        const float* __restrict__ feat,
        const int*   __restrict__ nbr,
        const float4* __restrict__ geomF,
        const int*   __restrict__ geomI,
        const float* __restrict__ dense,
        ushort* __restrict__ A,
        int m0, int m1, int Ktot) {
    constexpr int SP = 72;              // row stride (elems): 144B, 16B-aligned
    constexpr int NT = CIN / 16;        // 6 (cin96) or 4 (cin64)
    __shared__ ushort S[64*SP];
    __shared__ ushort FW[CIN*SP];
    int l = threadIdx.x;
    int n = m0 + blockIdx.x;
    if (n >= m1) return;

    // 1. zero S (pad cols included; only k=0..63 are ever read)
    {
        uint4 z = make_uint4(0,0,0,0);
        uint4* Sv = (uint4*)S;
#pragma unroll
        for (int i = 0; i < (64*SP*2)/(16*64); ++i)   // 9 iters
            Sv[l + 64*i] = z;
    }
    // 2. geometry -> S scatter (lane l owns neighbor k=l; distinct columns)
    size_t t = (size_t)n * KNBR + l;
    float4 g = geomF[t];
    int cell = geomI[t];
    int j = nbr[t];
    {
        float win = g.x;
        float x1 = g.y, y1 = g.z, z1 = g.w;
        float x0 = 1.f-x1, y0 = 1.f-y1, z0 = 1.f-z1;
        float w00 = y0*z0*win, w01 = y0*z1*win, w10 = y1*z0*win, w11 = y1*z1*win;
        ushort* Sc = S + cell*SP + l;
        Sc[0*SP]  = f2bf(x0*w00);
        Sc[1*SP]  = f2bf(x0*w01);
        Sc[4*SP]  = f2bf(x0*w10);
        Sc[5*SP]  = f2bf(x0*w11);
        Sc[16*SP] = f2bf(x1*w00);
        Sc[17*SP] = f2bf(x1*w01);
        Sc[20*SP] = f2bf(x1*w10);
        Sc[21*SP] = f2bf(x1*w11);
    }
    // 3. FW build: lane l streams neighbor j's feature row -> FW[ch][l]
    {
        const float* frow = feat + (size_t)j * CIN;
#pragma unroll
        for (int c4 = 0; c4 < CIN; c4 += 4) {
            float4 v = *(const float4*)(frow + c4);
            FW[(c4+0)*SP + l] = f2bf(v.x);
            FW[(c4+1)*SP + l] = f2bf(v.y);
            FW[(c4+2)*SP + l] = f2bf(v.z);
            FW[(c4+3)*SP + l] = f2bf(v.w);
        }
    }
    // 4. per-particle MFMA: A_t[cell,ch] = sum_k S[cell,k]*FW[ch,k]
    //    (wave-synchronous: in-wave DS ops are ordered, no barrier needed)
    int lm = l & 15, koct = l >> 4;
    f32x4 acc[4][NT];
#pragma unroll
    for (int mt = 0; mt < 4; ++mt)
#pragma unroll
        for (int nt = 0; nt < NT; ++nt)
            acc[mt][nt] = (f32x4){0.f, 0.f, 0.f, 0.f};
#pragma unroll
    for (int ks = 0; ks < 2; ++ks) {
        bf16x8 sf[4];
#pragma unroll
        for (int mt = 0; mt < 4; ++mt)
            sf[mt] = *(const bf16x8*)&S[(mt*16 + lm)*SP + ks*32 + koct*8];
#pragma unroll
        for (int nt = 0; nt < NT; ++nt) {
            bf16x8 ff = *(const bf16x8*)&FW[(nt*16 + lm)*SP + ks*32 + koct*8];
#pragma unroll
            for (int mt = 0; mt < 4; ++mt)
                acc[mt][nt] = __builtin_amdgcn_mfma_f32_16x16x32_bf16(
                                  sf[mt], ff, acc[mt][nt], 0, 0, 0);
        }
    }
    // 5. C/D layout: col(=ch)=lane&15, row(=cell)=(lane>>4)*4+reg -> A_t
    //    stored transposed [ch][cell] (reuses FW region, reads done above)
    ushort* AT = FW;
#pragma unroll
    for (int nt = 0; nt < NT; ++nt)
#pragma unroll
        for (int mt = 0; mt < 4; ++mt) {
            u16x4 pk;
            pk.x = f2bf(acc[mt][nt][0]);
            pk.y = f2bf(acc[mt][nt][1]);
            pk.z = f2bf(acc[mt][nt][2]);
            pk.w = f2bf(acc[mt][nt][3]);
            *(u16x4*)&AT[(nt*16 + lm)*SP + mt*16 + koct*4] = pk;
        }
    // 6. coalesced writeback, k' = ch*64 + cell
    ushort* Arow = A + (size_t)(n - m0) * Ktot;
#pragma unroll
    for (int it = 0; it < CIN/8; ++it) {
        int i = l + 64*it;
        int ch = i >> 3, cc = (i & 7) * 8;
        uint4 v = *(const uint4*)&AT[ch*SP + cc];
        *(uint4*)&Arow[(ch << 6) + cc] = v;
    }
    // 7. dense tail
#pragma unroll
    for (int c0 = 0; c0 < CIN; c0 += 64) {
        int ch = c0 + l;
        if (ch < CIN) Arow[64*CIN + ch] = f2bf(dense[(size_t)n*CIN + ch]);
    }
}

// dense_1 = fluid_vel @ W_d1 + b_d1 -> out1 columns [64..96)
__global__ void dense1_kernel(const float* __restrict__ vel,
                              const float* __restrict__ Wd,
                              const float* __restrict__ bd,
                              float* __restrict__ out1, int M) {
    int t = blockIdx.x * blockDim.x + threadIdx.x;
    if (t >= M*32) return;
    int n = t >> 5, c = t & 31;
    float v = bd[c] + vel[n*3+0]*Wd[c] + vel[n*3+1]*Wd[32+c] + vel[n*3+2]*Wd[64+c];
    out1[(size_t)n*96 + 64 + c] = v;
}

// Transpose + bf16 weights: Wt[n][k]. perm=1 remaps conv K to k'=ch*64+cell.
__global__ void wprep_kernel(const float* __restrict__ Wc, int Kc,
                             const float* __restrict__ Wd,
                             int N, ushort* __restrict__ Wt, int Ktot, int perm) {
    int t = blockIdx.x * blockDim.x + threadIdx.x;
    if (t >= N * Ktot) return;
    int nn = t / Ktot, k = t - nn * Ktot;
    float v;
    if (k < Kc) {
        int row = k;
        if (perm) {
            int cinl = Kc >> 6;
            int ch = k >> 6, cl = k & 63;
            row = cl * cinl + ch;
        }
        v = Wc[(size_t)row*N + nn];
    } else {
        v = Wd[(size_t)(k-Kc)*N + nn];
    }
    Wt[(size_t)nn*Ktot + k] = f2bf(v);
}

// LDS-free bf16 MFMA GEMM: out[m, ocol+c] = f(A[m,:] @ Wt^T + b1 (+b2) (+res)).
template<int NCT>
__global__ __launch_bounds__(256) void mfma_gemm_kernel(
        const ushort* __restrict__ A, int Ktot,
        const ushort* __restrict__ Wt,
        const float* __restrict__ b1, const float* __restrict__ b2,
        const float* __restrict__ res,
        float* __restrict__ out, int ostride, int ocol,
        int m_base, int relu) {
    __shared__ float red[4][16][NCT*16 + 2];
    int tid = threadIdx.x;
    int wave = tid >> 6, l = tid & 63;
    int m0 = blockIdx.x * 16;
    int lm = l & 15;
    int lk = l >> 4;
    f32x4 acc[NCT];
#pragma unroll
    for (int ct = 0; ct < NCT; ++ct) acc[ct] = (f32x4){0.f, 0.f, 0.f, 0.f};

    int nks = Ktot >> 5;
    const ushort* Arow = A  + (size_t)(m0 + lm) * Ktot + lk*8;
    const ushort* Wrow = Wt + (size_t)lm * Ktot + lk*8;
    for (int ks = wave; ks < nks; ks += 4) {
        int k0 = ks * 32;
        bf16x8 a = *(const bf16x8*)(Arow + k0);
#pragma unroll
        for (int ct = 0; ct < NCT; ++ct) {
            bf16x8 b = *(const bf16x8*)(Wrow + (size_t)ct*16*Ktot + k0);
            acc[ct] = __builtin_amdgcn_mfma_f32_16x16x32_bf16(a, b, acc[ct], 0, 0, 0);
        }
    }

#pragma unroll
    for (int ct = 0; ct < NCT; ++ct)
#pragma unroll
        for (int r = 0; r < 4; ++r)
            red[wave][lk*4 + r][ct*16 + lm] = acc[ct][r];
    __syncthreads();

    const int NTOT = NCT * 16;
    for (int idx = tid; idx < 16*NTOT; idx += 256) {
        int row = idx / NTOT, col = idx - row*NTOT;
        float v = red[0][row][col] + red[1][row][col]
                + red[2][row][col] + red[3][row][col];
        int n_abs = m_base + m0 + row;
        v += b1[col];
        if (b2) v += b2[col];
        if (res) v += res[(size_t)n_abs*64 + col];
        if (relu) v = fmaxf(v, 0.f);
        out[(size_t)n_abs*ostride + ocol + col] = v;
    }
}

// Final layer (N=3): per-wave GEMV over bf16 A (k'=ch*64+cell order),
// fp32 W staged in LDS with the matching permutation.
#define K4TOT 4160
__global__ __launch_bounds__(256) void gemv3_kernel(
        const ushort* __restrict__ A,
        const float* __restrict__ Wa,
        const float* __restrict__ Wb,
        const float* __restrict__ b1, const float* __restrict__ b2,
        float* __restrict__ out, int m_base, int rows) {
    __shared__ float Wsh[K4TOT*3];
    int tid = threadIdx.x;
    for (int k = tid; k < K4TOT; k += 256) {
        int s;
        if (k < 4096) {
            int ch = k >> 6, cl = k & 63;
            s = (cl*64 + ch) * 3;
            Wsh[k*3+0] = Wa[s+0];
            Wsh[k*3+1] = Wa[s+1];
            Wsh[k*3+2] = Wa[s+2];
        } else {
            s = (k - 4096) * 3;
            Wsh[k*3+0] = Wb[s+0];
            Wsh[k*3+1] = Wb[s+1];
            Wsh[k*3+2] = Wb[s+2];
        }
    }
    __syncthreads();
    int wv = tid >> 6, l = tid & 63;
    int m = blockIdx.x*4 + wv;
    if (m >= rows) return;
    const ushort* Arow = A + (size_t)m * K4TOT;
    float a0 = 0.f, a1 = 0.f, a2 = 0.f;
#pragma unroll 4
    for (int i = 0; i < 32; ++i) {
        int k = 2*l + 128*i;
        uint pr = *(const uint*)(Arow + k);
        float x0 = bfbits2f(pr << 16);
        float x1 = bfbits2f(pr & 0xFFFF0000u);
        a0 += x0*Wsh[k*3+0] + x1*Wsh[(k+1)*3+0];
        a1 += x0*Wsh[k*3+1] + x1*Wsh[(k+1)*3+1];
        a2 += x0*Wsh[k*3+2] + x1*Wsh[(k+1)*3+2];
    }
    {
        int k = 4096 + l;
        float x = bfbits2f(((uint)Arow[k]) << 16);
        a0 += x*Wsh[k*3+0];
        a1 += x*Wsh[k*3+1];
        a2 += x*Wsh[k*3+2];
    }
#pragma unroll
    for (int off = 32; off; off >>= 1) {
        a0 += __shfl_down(a0, off, 64);
        a1 += __shfl_down(a1, off, 64);
        a2 += __shfl_down(a2, off, 64);
    }
    if (l == 0) {
        int n = m_base + m;
        out[n*3+0] = a0 + b1[0] + b2[0];
        out[n*3+1] = a1 + b1[1] + b2[1];
        out[n*3+2] = a2 + b1[2] + b2[2];
    }
}

extern "C" void kernel_launch(void* const* d_in, const int* in_sizes, int n_in,
                              void* d_out, int out_size, void* d_ws, size_t ws_size,
                              hipStream_t stream) {
    const float* fluid_pos = (const float*)d_in[0];
    const float* wall_pos  = (const float*)d_in[1];
    const float* fluid_vel = (const float*)d_in[2];
    const float* wall_nrm  = (const float*)d_in[3];
    const int*   nbr_wf    = (const int*)d_in[4];
    const int*   nbr_ff    = (const int*)d_in[6];
    const float* W_wall1   = (const float*)d_in[8];
    const float* b_wall1   = (const float*)d_in[9];
    const float* W_fluid1  = (const float*)d_in[10];
    const float* b_fluid1  = (const float*)d_in[11];
    const float* W_d1      = (const float*)d_in[12];
    const float* b_d1      = (const float*)d_in[13];
    const float* W_c2      = (const float*)d_in[14];
    const float* b_c2      = (const float*)d_in[15];
    const float* W_d2      = (const float*)d_in[16];
    const float* b_d2      = (const float*)d_in[17];
    const float* W_c3      = (const float*)d_in[18];
    const float* b_c3      = (const float*)d_in[19];
    const float* W_d3      = (const float*)d_in[20];
    const float* b_d3      = (const float*)d_in[21];
    const float* W_c4      = (const float*)d_in[22];
    const float* b_c4      = (const float*)d_in[23];
    const float* W_d4      = (const float*)d_in[24];
    const float* b_d4      = (const float*)d_in[25];

    const int M = M_FLUID;
    char* ws = (char*)d_ws;
    size_t off = 0;
    auto carve = [&](size_t bytes) {
        char* p = ws + off;
        off = (off + bytes + 255) & ~(size_t)255;
        return p;
    };
    float4* gF_ff = (float4*)carve((size_t)M*KNBR*sizeof(float4));
    int*    gI_ff = (int*)   carve((size_t)M*KNBR*4);
    float4* gF_wf = (float4*)carve((size_t)M*KNBR*sizeof(float4));
    int*    gI_wf = (int*)   carve((size_t)M*KNBR*4);
    float*  out1  = (float*) carve((size_t)M*96*4);
    float*  out2  = (float*) carve((size_t)M*64*4);
    float*  out3  = (float*) carve((size_t)M*64*4);
    ushort* Wt1a  = (ushort*)carve((size_t)32*192*2);
    ushort* Wt1b  = (ushort*)carve((size_t)32*192*2);
    ushort* Wt2   = (ushort*)carve((size_t)64*6240*2);
    ushort* Wt3   = (ushort*)carve((size_t)64*4160*2);
    ushort* Abuf  = (ushort*)(ws + off);
    size_t availA = (ws_size > off) ? (ws_size - off) : 0;

    auto chunkR = [&](int Ktot) -> int {
        size_t r = availA / ((size_t)Ktot * 2);   // bf16 A
        if (r > (size_t)M) r = (size_t)M;
        r &= ~(size_t)63;
        if (r < 64) r = 64;
        return (int)r;
    };

    // ---- weight prep (bf16 transpose; perm=1 matches abuild_s k-order)
    {
        int t;
        t = 32*192;  wprep_kernel<<<(t+255)/256, 256, 0, stream>>>(W_wall1, 192, nullptr, 32, Wt1a, 192, 0);
        t = 32*192;  wprep_kernel<<<(t+255)/256, 256, 0, stream>>>(W_fluid1, 192, nullptr, 32, Wt1b, 192, 0);
        t = 64*6240; wprep_kernel<<<(t+255)/256, 256, 0, stream>>>(W_c2, 6144, W_d2, 64, Wt2, 6240, 1);
        t = 64*4160; wprep_kernel<<<(t+255)/256, 256, 0, stream>>>(W_c3, 4096, W_d3, 64, Wt3, 4160, 1);
    }
    {   // geometry (reused across all layers sharing the neighbor list)
        int total = M * KNBR, thr = 256, blk = (total + thr - 1) / thr;
        geom_kernel<<<blk, thr, 0, stream>>>(fluid_pos, fluid_pos, nbr_ff, gF_ff, gI_ff, M, 1);
        geom_kernel<<<blk, thr, 0, stream>>>(wall_pos,  fluid_pos, nbr_wf, gF_wf, gI_wf, M, 0);
    }
    dense1_kernel<<<(M*32 + 255)/256, 256, 0, stream>>>(fluid_vel, W_d1, b_d1, out1, M);

    // ---- layer 1a: wall cconv -> out1[:, 0:32]
    {
        int Ktot = 192, R = chunkR(Ktot);
        for (int m0 = 0; m0 < M; m0 += R) {
            int rows = (M - m0 < R) ? (M - m0) : R;
            abuild_kernel<3,64><<<(rows+63)/64, dim3(3,64), 0, stream>>>(
                wall_nrm, nbr_wf, gF_wf, gI_wf, Abuf, m0, m0+rows, Ktot);
            mfma_gemm_kernel<2><<<rows/16, 256, 0, stream>>>(
                Abuf, Ktot, Wt1a, b_wall1, nullptr, nullptr,
                out1, 96, 0, m0, 1);
        }
    }
    // ---- layer 1b: fluid cconv -> out1[:, 32:64]
    {
        int Ktot = 192, R = chunkR(Ktot);
        for (int m0 = 0; m0 < M; m0 += R) {
            int rows = (M - m0 < R) ? (M - m0) : R;
            abuild_kernel<3,64><<<(rows+63)/64, dim3(3,64), 0, stream>>>(
                fluid_vel, nbr_ff, gF_ff, gI_ff, Abuf, m0, m0+rows, Ktot);
            mfma_gemm_kernel<2><<<rows/16, 256, 0, stream>>>(
                Abuf, Ktot, Wt1b, b_fluid1, nullptr, nullptr,
                out1, 96, 32, m0, 1);
        }
    }
    // ---- layer 2: cin=96 -> out2
    {
        int Ktot = 6240, R = chunkR(Ktot);
        for (int m0 = 0; m0 < M; m0 += R) {
            int rows = (M - m0 < R) ? (M - m0) : R;
            abuild_s_kernel<96><<<rows, 64, 0, stream>>>(
                out1, nbr_ff, gF_ff, gI_ff, out1, Abuf, m0, m0+rows, Ktot);
            mfma_gemm_kernel<4><<<rows/16, 256, 0, stream>>>(
                Abuf, Ktot, Wt2, b_c2, b_d2, nullptr,
                out2, 64, 0, m0, 1);
        }
    }
    // ---- layer 3: cin=64, residual -> out3
    {
        int Ktot = 4160, R = chunkR(Ktot);
        for (int m0 = 0; m0 < M; m0 += R) {
            int rows = (M - m0 < R) ? (M - m0) : R;
            abuild_s_kernel<64><<<rows, 64, 0, stream>>>(
                out2, nbr_ff, gF_ff, gI_ff, out2, Abuf, m0, m0+rows, Ktot);
            mfma_gemm_kernel<4><<<rows/16, 256, 0, stream>>>(
                Abuf, Ktot, Wt3, b_c3, b_d3, out2,
                out3, 64, 0, m0, 1);
        }
    }
    // ---- layer 4: cin=64, N=3 -> d_out
    {
        int Ktot = K4TOT, R = chunkR(Ktot);
        for (int m0 = 0; m0 < M; m0 += R) {
            int rows = (M - m0 < R) ? (M - m0) : R;
            abuild_s_kernel<64><<<rows, 64, 0, stream>>>(
                out3, nbr_ff, gF_ff, gI_ff, out3, Abuf, m0, m0+rows, Ktot);
            gemv3_kernel<<<(rows+3)/4, 256, 0, stream>>>(
                Abuf, W_c4, W_d4, b_c4, b_d4, (float*)d_out, m0, rows);
        }
    }
}

// Round 4
// 596.429 us; speedup vs baseline: 4.9846x; 1.0454x over previous
//
#include <hip/hip_runtime.h>
#include <hip/hip_bf16.h>

// ---------------------------------------------------------------------------
// Net_19378892440061: ContinuousConv fluid network, Round 4.
// Changes vs Round 3:
//  - Layer 4 restructured (cout=3 < cin): G[j,cell,c] = out3[j,:] . W_c4[cell,:,c]
//    precomputed (fp32, 12.3 MB), then a per-pair 8-cell gather-FMA kernel
//    produces the output directly. abuild_s L4 + gemv3 + 266 MB A traffic gone.
//  - mfma_gemm: 8 waves/block (512 thr), 8-way K split, explicit 2-deep
//    software pipeline (prefetch next A/B fragments before current MFMAs).
// ---------------------------------------------------------------------------

#define M_FLUID 16000
#define KNBR 64

typedef __attribute__((ext_vector_type(8))) short bf16x8;
typedef __attribute__((ext_vector_type(4))) float f32x4;
typedef __attribute__((ext_vector_type(4))) unsigned short u16x4;

__device__ __forceinline__ ushort f2bf(float f) {
    __hip_bfloat16 h = __float2bfloat16(f);   // RNE
    return *(ushort*)&h;
}

__device__ __forceinline__ float sgnf(float v) {
    return (v > 0.f) ? 1.f : ((v < 0.f) ? -1.f : 0.f);
}

// Volume-preserving ball->cube map (matches reference _ball_to_cube, fp32).
__device__ __forceinline__ void ball_to_cube(float x, float y, float z,
                                             float& xc, float& yc, float& zc) {
    const float eps = 1e-12f;
    float sq  = x*x + y*y + z*z;
    float nrm = sqrtf(fmaxf(sq, eps));
    float rho = sqrtf(fmaxf(x*x + y*y, eps));
    bool  top = (1.25f*z*z > x*x + y*y);
    float s_top = sqrtf(3.0f*nrm/(nrm + fabsf(z)));
    float xs = top ? x*s_top : x*nrm/rho;
    float ys = top ? y*s_top : y*nrm/rho;
    float zs = top ? sgnf(z)*nrm : 1.5f*z;
    if (sq < eps) { xs = 0.f; ys = 0.f; zs = 0.f; }
    float rxy = sqrtf(fmaxf(xs*xs + ys*ys, eps));
    bool use_x = fabsf(ys) <= fabsf(xs);
    float dx = (use_x && fabsf(xs) > eps) ? xs : 1.0f;
    float dy = (!use_x && fabsf(ys) > eps) ? ys : 1.0f;
    const float c4pi = 1.2732395447351628f;  // 4/pi
    float xc_, yc_;
    if (use_x) {
        xc_ = sgnf(xs)*rxy;
        yc_ = sgnf(xs)*rxy*c4pi*atanf(ys/dx);
    } else {
        xc_ = sgnf(ys)*rxy*c4pi*atanf(xs/dy);
        yc_ = sgnf(ys)*rxy;
    }
    if (xs*xs + ys*ys < eps) { xc_ = 0.f; yc_ = 0.f; }
    xc = xc_; yc = yc_; zc = zs;
}

// Per-pair geometry: win (0 if invalid), trilinear fractions f, packed cell.
__global__ void geom_kernel(const float* __restrict__ pos_in,
                            const float* __restrict__ pos_out,
                            const int*  __restrict__ nbr,
                            float4* __restrict__ geomF,
                            int*    __restrict__ geomI,
                            int M, int excl_self) {
    int t = blockIdx.x * blockDim.x + threadIdx.x;
    if (t >= M * KNBR) return;
    int n = t >> 6;
    int k = t & 63;
    int j = nbr[t];
    float px = pos_out[n*3+0], py = pos_out[n*3+1], pz = pos_out[n*3+2];
    float qx = pos_in[(size_t)j*3+0], qy = pos_in[(size_t)j*3+1], qz = pos_in[(size_t)j*3+2];
    float dx = qx - px, dy = qy - py, dz = qz - pz;

    bool valid;
    if (k == 0) {
        // reproduce numpy fp32 distance exactly (no FMA contraction)
#pragma clang fp contract(off)
        float d2f = dx*dx + dy*dy;
        d2f = d2f + dz*dz;
        double d2 = (double)d2f;
        const double RADIUS_D = 0.5*(6.0*1.5*0.025);  // 0.1125
        valid = d2 < RADIUS_D*RADIUS_D;
        if (excl_self) valid = valid && (d2 > 1e-18);
    } else {
        valid = (j != 0);  // ascending neighbor ids: 0 past slot 0 == padding
    }

    const float Rf = (float)(0.5*(6.0*1.5*0.025));
    float ux = dx / Rf, uy = dy / Rf, uz = dz / Rf;
    float r2 = ux*ux + uy*uy; r2 += uz*uz;
    float w1 = 1.f - r2;
    float win = fminf(fmaxf(w1*w1*w1, 0.f), 1.f);

    float bx, by, bz;
    ball_to_cube(ux, uy, uz, bx, by, bz);
    float cx = fminf(fmaxf((bx*0.5f + 0.5f)*3.f, 0.f), 3.f);
    float cy = fminf(fmaxf((by*0.5f + 0.5f)*3.f, 0.f), 3.f);
    float cz = fminf(fmaxf((bz*0.5f + 0.5f)*3.f, 0.f), 3.f);
    float ix = fminf(fmaxf(floorf(cx), 0.f), 2.f);
    float iy = fminf(fmaxf(floorf(cy), 0.f), 2.f);
    float iz = fminf(fmaxf(floorf(cz), 0.f), 2.f);
    float fx = cx - ix, fy = cy - iy, fz = cz - iz;
    int cell = ((int)ix*4 + (int)iy)*4 + (int)iz;

    geomF[t] = make_float4(valid ? win : 0.f, fx, fy, fz);
    geomI[t] = cell;
}

// ---- Layer-1 path (cin=3): scalar scatter, k = cell*3+ch order.
template<int CIN, int P>
__global__ void abuild_kernel(const float* __restrict__ feat,
                              const int*   __restrict__ nbr,
                              const float4* __restrict__ geomF,
                              const int*   __restrict__ geomI,
                              ushort* __restrict__ A,
                              int m0, int m1, int Ktot) {
    __shared__ float Ash[P][64*CIN];
    int c = threadIdx.x;
    int p = threadIdx.y;
    int n = m0 + blockIdx.x * P + p;
    float* col = Ash[p];
#pragma unroll
    for (int cell = 0; cell < 64; ++cell) col[cell*CIN + c] = 0.f;
    if (n >= m1) return;

    const int*    nrow = nbr   + (size_t)n * KNBR;
    const float4* grow = geomF + (size_t)n * KNBR;
    const int*    irow = geomI + (size_t)n * KNBR;
    for (int k = 0; k < KNBR; ++k) {
        float4 g = grow[k];
        float win = g.x;
        if (win <= 0.f) continue;
        int j = nrow[k];
        int base = irow[k];
        float v = feat[(size_t)j*CIN + c] * win;
        float wx1 = g.y, wy1 = g.z, wz1 = g.w;
        float wx0 = 1.f - wx1, wy0 = 1.f - wy1, wz0 = 1.f - wz1;
        float w00 = wy0*wz0, w01 = wy0*wz1, w10 = wy1*wz0, w11 = wy1*wz1;
        float* cb = col + base*CIN + c;
        cb[0*CIN]  += wx0*w00*v;
        cb[1*CIN]  += wx0*w01*v;
        cb[4*CIN]  += wx0*w10*v;
        cb[5*CIN]  += wx0*w11*v;
        cb[16*CIN] += wx1*w00*v;
        cb[17*CIN] += wx1*w01*v;
        cb[20*CIN] += wx1*w10*v;
        cb[21*CIN] += wx1*w11*v;
    }
    ushort* Arow = A + (size_t)(n - m0) * Ktot;
#pragma unroll
    for (int cell = 0; cell < 64; ++cell) Arow[cell*CIN + c] = f2bf(col[cell*CIN + c]);
}

// ---- MFMA-scatter abuild for CIN in {64, 96}. One wave = one particle.
template<int CIN>
__global__ __launch_bounds__(64) void abuild_s_kernel(
        const float* __restrict__ feat,
        const int*   __restrict__ nbr,
        const float4* __restrict__ geomF,
        const int*   __restrict__ geomI,
        const float* __restrict__ dense,
        ushort* __restrict__ A,
        int m0, int m1, int Ktot) {
    constexpr int SP = 72;              // row stride (elems): 144B, 16B-aligned
    constexpr int NT = CIN / 16;        // 6 (cin96) or 4 (cin64)
    __shared__ ushort S[64*SP];
    __shared__ ushort FW[CIN*SP];
    int l = threadIdx.x;
    int n = m0 + blockIdx.x;
    if (n >= m1) return;

    // 1. zero S
    {
        uint4 z = make_uint4(0,0,0,0);
        uint4* Sv = (uint4*)S;
#pragma unroll
        for (int i = 0; i < (64*SP*2)/(16*64); ++i)   // 9 iters
            Sv[l + 64*i] = z;
    }
    // 2. geometry -> S scatter (lane l owns neighbor k=l; distinct columns)
    size_t t = (size_t)n * KNBR + l;
    float4 g = geomF[t];
    int cell = geomI[t];
    int j = nbr[t];
    {
        float win = g.x;
        float x1 = g.y, y1 = g.z, z1 = g.w;
        float x0 = 1.f-x1, y0 = 1.f-y1, z0 = 1.f-z1;
        float w00 = y0*z0*win, w01 = y0*z1*win, w10 = y1*z0*win, w11 = y1*z1*win;
        ushort* Sc = S + cell*SP + l;
        Sc[0*SP]  = f2bf(x0*w00);
        Sc[1*SP]  = f2bf(x0*w01);
        Sc[4*SP]  = f2bf(x0*w10);
        Sc[5*SP]  = f2bf(x0*w11);
        Sc[16*SP] = f2bf(x1*w00);
        Sc[17*SP] = f2bf(x1*w01);
        Sc[20*SP] = f2bf(x1*w10);
        Sc[21*SP] = f2bf(x1*w11);
    }
    // 3. FW build: lane l streams neighbor j's feature row -> FW[ch][l]
    {
        const float* frow = feat + (size_t)j * CIN;
#pragma unroll
        for (int c4 = 0; c4 < CIN; c4 += 4) {
            float4 v = *(const float4*)(frow + c4);
            FW[(c4+0)*SP + l] = f2bf(v.x);
            FW[(c4+1)*SP + l] = f2bf(v.y);
            FW[(c4+2)*SP + l] = f2bf(v.z);
            FW[(c4+3)*SP + l] = f2bf(v.w);
        }
    }
    // 4. per-particle MFMA: A_t[cell,ch] = sum_k S[cell,k]*FW[ch,k]
    int lm = l & 15, koct = l >> 4;
    f32x4 acc[4][NT];
#pragma unroll
    for (int mt = 0; mt < 4; ++mt)
#pragma unroll
        for (int nt = 0; nt < NT; ++nt)
            acc[mt][nt] = (f32x4){0.f, 0.f, 0.f, 0.f};
#pragma unroll
    for (int ks = 0; ks < 2; ++ks) {
        bf16x8 sf[4];
#pragma unroll
        for (int mt = 0; mt < 4; ++mt)
            sf[mt] = *(const bf16x8*)&S[(mt*16 + lm)*SP + ks*32 + koct*8];
#pragma unroll
        for (int nt = 0; nt < NT; ++nt) {
            bf16x8 ff = *(const bf16x8*)&FW[(nt*16 + lm)*SP + ks*32 + koct*8];
#pragma unroll
            for (int mt = 0; mt < 4; ++mt)
                acc[mt][nt] = __builtin_amdgcn_mfma_f32_16x16x32_bf16(
                                  sf[mt], ff, acc[mt][nt], 0, 0, 0);
        }
    }
    // 5. C/D: col(=ch)=lane&15, row(=cell)=(lane>>4)*4+reg -> AT[ch][cell]
    ushort* AT = FW;
#pragma unroll
    for (int nt = 0; nt < NT; ++nt)
#pragma unroll
        for (int mt = 0; mt < 4; ++mt) {
            u16x4 pk;
            pk.x = f2bf(acc[mt][nt][0]);
            pk.y = f2bf(acc[mt][nt][1]);
            pk.z = f2bf(acc[mt][nt][2]);
            pk.w = f2bf(acc[mt][nt][3]);
            *(u16x4*)&AT[(nt*16 + lm)*SP + mt*16 + koct*4] = pk;
        }
    // 6. coalesced writeback, k' = ch*64 + cell
    ushort* Arow = A + (size_t)(n - m0) * Ktot;
#pragma unroll
    for (int it = 0; it < CIN/8; ++it) {
        int i = l + 64*it;
        int ch = i >> 3, cc = (i & 7) * 8;
        uint4 v = *(const uint4*)&AT[ch*SP + cc];
        *(uint4*)&Arow[(ch << 6) + cc] = v;
    }
    // 7. dense tail
#pragma unroll
    for (int c0 = 0; c0 < CIN; c0 += 64) {
        int ch = c0 + l;
        if (ch < CIN) Arow[64*CIN + ch] = f2bf(dense[(size_t)n*CIN + ch]);
    }
}

// dense_1 = fluid_vel @ W_d1 + b_d1 -> out1 columns [64..96)
__global__ void dense1_kernel(const float* __restrict__ vel,
                              const float* __restrict__ Wd,
                              const float* __restrict__ bd,
                              float* __restrict__ out1, int M) {
    int t = blockIdx.x * blockDim.x + threadIdx.x;
    if (t >= M*32) return;
    int n = t >> 5, c = t & 31;
    float v = bd[c] + vel[n*3+0]*Wd[c] + vel[n*3+1]*Wd[32+c] + vel[n*3+2]*Wd[64+c];
    out1[(size_t)n*96 + 64 + c] = v;
}

// Transpose + bf16 weights: Wt[n][k]. perm=1 remaps conv K to k'=ch*64+cell.
__global__ void wprep_kernel(const float* __restrict__ Wc, int Kc,
                             const float* __restrict__ Wd,
                             int N, ushort* __restrict__ Wt, int Ktot, int perm) {
    int t = blockIdx.x * blockDim.x + threadIdx.x;
    if (t >= N * Ktot) return;
    int nn = t / Ktot, k = t - nn * Ktot;
    float v;
    if (k < Kc) {
        int row = k;
        if (perm) {
            int cinl = Kc >> 6;
            int ch = k >> 6, cl = k & 63;
            row = cl * cinl + ch;
        }
        v = Wc[(size_t)row*N + nn];
    } else {
        v = Wd[(size_t)(k-Kc)*N + nn];
    }
    Wt[(size_t)nn*Ktot + k] = f2bf(v);
}

// bf16 MFMA GEMM, 8 waves/block, 8-way K split, 2-deep software pipeline.
template<int NCT>
__global__ __launch_bounds__(512) void mfma_gemm_kernel(
        const ushort* __restrict__ A, int Ktot,
        const ushort* __restrict__ Wt,
        const float* __restrict__ b1, const float* __restrict__ b2,
        const float* __restrict__ res,
        float* __restrict__ out, int ostride, int ocol,
        int m_base, int relu) {
    __shared__ float red[8][16][NCT*16 + 2];
    int tid = threadIdx.x;
    int wave = tid >> 6, l = tid & 63;
    int m0 = blockIdx.x * 16;
    int lm = l & 15;
    int lk = l >> 4;
    f32x4 acc[NCT];
#pragma unroll
    for (int ct = 0; ct < NCT; ++ct) acc[ct] = (f32x4){0.f, 0.f, 0.f, 0.f};

    int nks = Ktot >> 5;
    const ushort* Arow = A  + (size_t)(m0 + lm) * Ktot + lk*8;
    const ushort* Wrow = Wt + (size_t)lm * Ktot + lk*8;

    int ks = wave;
    bf16x8 ac = {};
    bf16x8 bc[NCT] = {};
    if (ks < nks) {
        int k0 = ks * 32;
        ac = *(const bf16x8*)(Arow + k0);
#pragma unroll
        for (int ct = 0; ct < NCT; ++ct)
            bc[ct] = *(const bf16x8*)(Wrow + (size_t)ct*16*Ktot + k0);
    }
    while (ks < nks) {
        int ksn = ks + 8;
        bf16x8 an = {};
        bf16x8 bn[NCT] = {};
        if (ksn < nks) {
            int k0 = ksn * 32;
            an = *(const bf16x8*)(Arow + k0);
#pragma unroll
            for (int ct = 0; ct < NCT; ++ct)
                bn[ct] = *(const bf16x8*)(Wrow + (size_t)ct*16*Ktot + k0);
        }
#pragma unroll
        for (int ct = 0; ct < NCT; ++ct)
            acc[ct] = __builtin_amdgcn_mfma_f32_16x16x32_bf16(ac, bc[ct], acc[ct], 0, 0, 0);
        ac = an;
#pragma unroll
        for (int ct = 0; ct < NCT; ++ct) bc[ct] = bn[ct];
        ks = ksn;
    }

#pragma unroll
    for (int ct = 0; ct < NCT; ++ct)
#pragma unroll
        for (int r = 0; r < 4; ++r)
            red[wave][lk*4 + r][ct*16 + lm] = acc[ct][r];
    __syncthreads();

    const int NTOT = NCT * 16;
    for (int idx = tid; idx < 16*NTOT; idx += 512) {
        int row = idx / NTOT, col = idx - row*NTOT;
        float v = 0.f;
#pragma unroll
        for (int w = 0; w < 8; ++w) v += red[w][row][col];
        int n_abs = m_base + m0 + row;
        v += b1[col];
        if (b2) v += b2[col];
        if (res) v += res[(size_t)n_abs*64 + col];
        if (relu) v = fmaxf(v, 0.f);
        out[(size_t)n_abs*ostride + ocol + col] = v;
    }
}

// ---- Layer 4 (cout=3): G[j][cell][c] = sum_ch out3[j][ch] * W4[cell][ch][c]
// Block: 4 particles x 64 cells; W4 staged transposed [ch][cell][c] in LDS.
__global__ __launch_bounds__(256) void g4_kernel(
        const float* __restrict__ out3,
        const float* __restrict__ W4,     // [cell][ch][c] = [64][64][3]
        float* __restrict__ G, int M) {
    __shared__ float Wsh[64*192];         // [ch][cell*3+c]
    __shared__ float fsh[4][64];
    int tid = threadIdx.x;
    for (int i = tid; i < 64*192; i += 256) {
        int ch = i / 192, r = i - ch*192;
        int cell = r / 3, c = r - cell*3;
        Wsh[i] = W4[cell*192 + ch*3 + c];
    }
    int n0 = blockIdx.x * 4;
    {
        int p = tid >> 6, ch = tid & 63;
        int n = n0 + p;
        fsh[p][ch] = (n < M) ? out3[(size_t)n*64 + ch] : 0.f;
    }
    __syncthreads();
    int p = tid >> 6, cell = tid & 63;
    int n = n0 + p;
    if (n >= M) return;
    float c0 = 0.f, c1 = 0.f, c2 = 0.f;
    const float* Wc = Wsh + cell*3;
#pragma unroll 8
    for (int ch = 0; ch < 64; ++ch) {
        float f = fsh[p][ch];
        c0 += f * Wc[ch*192 + 0];
        c1 += f * Wc[ch*192 + 1];
        c2 += f * Wc[ch*192 + 2];
    }
    float* Gp = G + (size_t)n*192 + cell*3;
    Gp[0] = c0; Gp[1] = c1; Gp[2] = c2;
}

// out[n][c] = b_c4[c]+b_d4[c] + sum_ch out3[n][ch]*W_d4[ch][c]
//           + sum_k win_k * sum_{8 cells} tri_w * G[j_k][cell][c]
__global__ __launch_bounds__(256) void l4_scatter_kernel(
        const float* __restrict__ G,
        const float4* __restrict__ geomF,
        const int*   __restrict__ geomI,
        const int*   __restrict__ nbr,
        const float* __restrict__ out3,
        const float* __restrict__ Wd4,
        const float* __restrict__ b_c4, const float* __restrict__ b_d4,
        float* __restrict__ out, int M) {
    __shared__ float Wsh[192];
    int tid = threadIdx.x;
    if (tid < 192) Wsh[tid] = Wd4[tid];
    __syncthreads();
    int wv = tid >> 6, l = tid & 63;
    int n = blockIdx.x*4 + wv;
    if (n >= M) return;
    size_t t = (size_t)n * KNBR + l;
    float4 g = geomF[t];
    int cell = geomI[t];
    int j = nbr[t];
    float a0 = 0.f, a1 = 0.f, a2 = 0.f;
    float win = g.x;
    if (win > 0.f) {
        float x1 = g.y, y1 = g.z, z1 = g.w;
        float x0 = 1.f-x1, y0 = 1.f-y1, z0 = 1.f-z1;
        float w[8] = {x0*y0*z0, x0*y0*z1, x0*y1*z0, x0*y1*z1,
                      x1*y0*z0, x1*y0*z1, x1*y1*z0, x1*y1*z1};
        const int co[8] = {0,1,4,5,16,17,20,21};
        const float* Gj = G + (size_t)j*192;
#pragma unroll
        for (int i = 0; i < 8; ++i) {
            const float* Gc = Gj + (cell + co[i])*3;
            float ww = win * w[i];
            a0 += ww*Gc[0]; a1 += ww*Gc[1]; a2 += ww*Gc[2];
        }
    }
    {   // dense tail
        float v = out3[(size_t)n*64 + l];
        a0 += v*Wsh[l*3+0]; a1 += v*Wsh[l*3+1]; a2 += v*Wsh[l*3+2];
    }
#pragma unroll
    for (int off = 32; off; off >>= 1) {
        a0 += __shfl_down(a0, off, 64);
        a1 += __shfl_down(a1, off, 64);
        a2 += __shfl_down(a2, off, 64);
    }
    if (l == 0) {
        out[n*3+0] = a0 + b_c4[0] + b_d4[0];
        out[n*3+1] = a1 + b_c4[1] + b_d4[1];
        out[n*3+2] = a2 + b_c4[2] + b_d4[2];
    }
}

extern "C" void kernel_launch(void* const* d_in, const int* in_sizes, int n_in,
                              void* d_out, int out_size, void* d_ws, size_t ws_size,
                              hipStream_t stream) {
    const float* fluid_pos = (const float*)d_in[0];
    const float* wall_pos  = (const float*)d_in[1];
    const float* fluid_vel = (const float*)d_in[2];
    const float* wall_nrm  = (const float*)d_in[3];
    const int*   nbr_wf    = (const int*)d_in[4];
    const int*   nbr_ff    = (const int*)d_in[6];
    const float* W_wall1   = (const float*)d_in[8];
    const float* b_wall1   = (const float*)d_in[9];
    const float* W_fluid1  = (const float*)d_in[10];
    const float* b_fluid1  = (const float*)d_in[11];
    const float* W_d1      = (const float*)d_in[12];
    const float* b_d1      = (const float*)d_in[13];
    const float* W_c2      = (const float*)d_in[14];
    const float* b_c2      = (const float*)d_in[15];
    const float* W_d2      = (const float*)d_in[16];
    const float* b_d2      = (const float*)d_in[17];
    const float* W_c3      = (const float*)d_in[18];
    const float* b_c3      = (const float*)d_in[19];
    const float* W_d3      = (const float*)d_in[20];
    const float* b_d3      = (const float*)d_in[21];
    const float* W_c4      = (const float*)d_in[22];
    const float* b_c4      = (const float*)d_in[23];
    const float* W_d4      = (const float*)d_in[24];
    const float* b_d4      = (const float*)d_in[25];

    const int M = M_FLUID;
    char* ws = (char*)d_ws;
    size_t off = 0;
    auto carve = [&](size_t bytes) {
        char* p = ws + off;
        off = (off + bytes + 255) & ~(size_t)255;
        return p;
    };
    float4* gF_ff = (float4*)carve((size_t)M*KNBR*sizeof(float4));
    int*    gI_ff = (int*)   carve((size_t)M*KNBR*4);
    float4* gF_wf = (float4*)carve((size_t)M*KNBR*sizeof(float4));
    int*    gI_wf = (int*)   carve((size_t)M*KNBR*4);
    float*  out1  = (float*) carve((size_t)M*96*4);
    float*  out2  = (float*) carve((size_t)M*64*4);
    float*  out3  = (float*) carve((size_t)M*64*4);
    float*  Gbuf  = (float*) carve((size_t)M*192*4);
    ushort* Wt1a  = (ushort*)carve((size_t)32*192*2);
    ushort* Wt1b  = (ushort*)carve((size_t)32*192*2);
    ushort* Wt2   = (ushort*)carve((size_t)64*6240*2);
    ushort* Wt3   = (ushort*)carve((size_t)64*4160*2);
    ushort* Abuf  = (ushort*)(ws + off);
    size_t availA = (ws_size > off) ? (ws_size - off) : 0;

    auto chunkR = [&](int Ktot) -> int {
        size_t r = availA / ((size_t)Ktot * 2);   // bf16 A
        if (r > (size_t)M) r = (size_t)M;
        r &= ~(size_t)63;
        if (r < 64) r = 64;
        return (int)r;
    };

    // ---- weight prep (bf16 transpose; perm=1 matches abuild_s k-order)
    {
        int t;
        t = 32*192;  wprep_kernel<<<(t+255)/256, 256, 0, stream>>>(W_wall1, 192, nullptr, 32, Wt1a, 192, 0);
        t = 32*192;  wprep_kernel<<<(t+255)/256, 256, 0, stream>>>(W_fluid1, 192, nullptr, 32, Wt1b, 192, 0);
        t = 64*6240; wprep_kernel<<<(t+255)/256, 256, 0, stream>>>(W_c2, 6144, W_d2, 64, Wt2, 6240, 1);
        t = 64*4160; wprep_kernel<<<(t+255)/256, 256, 0, stream>>>(W_c3, 4096, W_d3, 64, Wt3, 4160, 1);
    }
    {   // geometry (reused across all layers sharing the neighbor list)
        int total = M * KNBR, thr = 256, blk = (total + thr - 1) / thr;
        geom_kernel<<<blk, thr, 0, stream>>>(fluid_pos, fluid_pos, nbr_ff, gF_ff, gI_ff, M, 1);
        geom_kernel<<<blk, thr, 0, stream>>>(wall_pos,  fluid_pos, nbr_wf, gF_wf, gI_wf, M, 0);
    }
    dense1_kernel<<<(M*32 + 255)/256, 256, 0, stream>>>(fluid_vel, W_d1, b_d1, out1, M);

    // ---- layer 1a: wall cconv -> out1[:, 0:32]
    {
        int Ktot = 192, R = chunkR(Ktot);
        for (int m0 = 0; m0 < M; m0 += R) {
            int rows = (M - m0 < R) ? (M - m0) : R;
            abuild_kernel<3,64><<<(rows+63)/64, dim3(3,64), 0, stream>>>(
                wall_nrm, nbr_wf, gF_wf, gI_wf, Abuf, m0, m0+rows, Ktot);
            mfma_gemm_kernel<2><<<rows/16, 512, 0, stream>>>(
                Abuf, Ktot, Wt1a, b_wall1, nullptr, nullptr,
                out1, 96, 0, m0, 1);
        }
    }
    // ---- layer 1b: fluid cconv -> out1[:, 32:64]
    {
        int Ktot = 192, R = chunkR(Ktot);
        for (int m0 = 0; m0 < M; m0 += R) {
            int rows = (M - m0 < R) ? (M - m0) : R;
            abuild_kernel<3,64><<<(rows+63)/64, dim3(3,64), 0, stream>>>(
                fluid_vel, nbr_ff, gF_ff, gI_ff, Abuf, m0, m0+rows, Ktot);
            mfma_gemm_kernel<2><<<rows/16, 512, 0, stream>>>(
                Abuf, Ktot, Wt1b, b_fluid1, nullptr, nullptr,
                out1, 96, 32, m0, 1);
        }
    }
    // ---- layer 2: cin=96 -> out2
    {
        int Ktot = 6240, R = chunkR(Ktot);
        for (int m0 = 0; m0 < M; m0 += R) {
            int rows = (M - m0 < R) ? (M - m0) : R;
            abuild_s_kernel<96><<<rows, 64, 0, stream>>>(
                out1, nbr_ff, gF_ff, gI_ff, out1, Abuf, m0, m0+rows, Ktot);
            mfma_gemm_kernel<4><<<rows/16, 512, 0, stream>>>(
                Abuf, Ktot, Wt2, b_c2, b_d2, nullptr,
                out2, 64, 0, m0, 1);
        }
    }
    // ---- layer 3: cin=64, residual -> out3
    {
        int Ktot = 4160, R = chunkR(Ktot);
        for (int m0 = 0; m0 < M; m0 += R) {
            int rows = (M - m0 < R) ? (M - m0) : R;
            abuild_s_kernel<64><<<rows, 64, 0, stream>>>(
                out2, nbr_ff, gF_ff, gI_ff, out2, Abuf, m0, m0+rows, Ktot);
            mfma_gemm_kernel<4><<<rows/16, 512, 0, stream>>>(
                Abuf, Ktot, Wt3, b_c3, b_d3, out2,
                out3, 64, 0, m0, 1);
        }
    }
    // ---- layer 4 (cout=3): G precompute + per-pair gather
    g4_kernel<<<(M+3)/4, 256, 0, stream>>>(out3, W_c4, Gbuf, M);
    l4_scatter_kernel<<<(M+3)/4, 256, 0, stream>>>(
        Gbuf, gF_ff, gI_ff, nbr_ff, out3, W_d4, b_c4, b_d4, (float*)d_out, M);
}